// Round 6
// baseline (479.631 us; speedup 1.0000x reference)
//
#include <hip/hip_runtime.h>
#include <hip/hip_bf16.h>
#include <stdint.h>

// B=32, T=512, D=1024, H=16, HD=64
#define NTOK 16384

typedef _Float16 f16;
typedef f16   f16x8 __attribute__((ext_vector_type(8)));
typedef float f32x4 __attribute__((ext_vector_type(4)));

__device__ __forceinline__ float bf2f(ushort h){
  union { uint32_t u; float f; } v; v.u = ((uint32_t)h) << 16; return v.f;
}
__device__ __forceinline__ ushort f2bf(float f){
  union { float f; uint32_t u; } v; v.f = f;
  uint32_t u = v.u;
  return (ushort)((u + 0x7FFFu + ((u >> 16) & 1u)) >> 16);  // RNE
}
__device__ __forceinline__ ushort f2h(float f){          // fp32 -> fp16 bits (RNE)
  return __builtin_bit_cast(ushort, (f16)f);
}
__device__ __forceinline__ f16x8 ld16(const ushort* p){  // 8 fp16
  uint4 u = *(const uint4*)p;
  return __builtin_bit_cast(f16x8, u);
}
// dtype-flexible fp32 load: fp32 path direct, bf16 path converts
__device__ __forceinline__ float ldf(const void* p, size_t idx, int isf32){
  if (isf32) return ((const float*)p)[idx];
  return bf2f(((const ushort*)p)[idx]);
}

// XOR-swizzled [*][64] fp16 tile in LDS (attention): element (row,col) at
//   row*64 + ((col>>3) ^ (row&7))*8 + (col&7)
__device__ __forceinline__ const ushort* swz(const ushort* base, uint row, uint chunk){
  return base + (size_t)row*64u + (size_t)((chunk ^ (row & 7u))*8u);
}

// XOR-swizzled [*][32] fp16 tile (GEMM): 4 chunks/row, swizzle (row>>1)&3
// -> a wave's b128 fragment read (rows l15, fixed chunk=quad) spreads over
//    8 distinct 16B slots per 128B line-pair: 2 lanes/slot = conflict-free.
__device__ __forceinline__ const ushort* swz32(const ushort* base, uint row, uint chunk){
  return base + (size_t)row*32u + (size_t)((chunk ^ ((row >> 1) & 3u))*8u);
}

// stage a 64x64 fp16 tile (row stride strideEl) into swizzled LDS via
// global_load_lds width-16 (attention staging). Source chunk pre-permuted.
__device__ __forceinline__ void stage64(const ushort* g, uint strideEl,
                                        ushort* ldsbase, uint tid){
  uint w = tid >> 6;
  #pragma unroll
  for (int i = 0; i < 2; ++i){
    uint lc  = i*256u + tid;               // dest chunk id (16B units)
    uint row = lc >> 3, cp = lc & 7u;
    uint c   = cp ^ (row & 7u);            // swizzled source chunk
    const ushort* gp = g + (size_t)row*strideEl + c*8u;
    ushort* lp = ldsbase + (size_t)(i*256u + w*64u)*8u;   // wave-uniform base
    __builtin_amdgcn_global_load_lds((const __attribute__((address_space(1))) void*)gp,
        (__attribute__((address_space(3))) void*)lp, 16, 0, 0);
  }
}

// stage a 128x32 fp16 half-tile (row stride K) into swizzled LDS (GEMM dbuf).
// 512 chunks of 16B, 2 loads/thread; source chunk = cp ^ ((row>>1)&3).
__device__ __forceinline__ void stage32(const ushort* g, int K,
                                        ushort* ldsbase, uint tid){
  uint w = tid >> 6;
  #pragma unroll
  for (int i = 0; i < 2; ++i){
    uint lc  = i*256u + tid;               // dest chunk id in [0,512)
    uint row = lc >> 2, cp = lc & 3u;
    uint c   = cp ^ ((row >> 1) & 3u);     // swizzled source chunk
    const ushort* gp = g + (size_t)row*(size_t)K + c*8u;
    ushort* lp = ldsbase + (size_t)(i*256u + w*64u)*8u;   // wave-uniform base
    __builtin_amdgcn_global_load_lds((const __attribute__((address_space(1))) void*)gp,
        (__attribute__((address_space(3))) void*)lp, 16, 0, 0);
  }
}

// ---------------- merged preprocessing (one dispatch) -------------------------
// blocks [0,8192):      x -> canonical fp16 (8 elems/thread)
// blocks [8192,8704):   transpose Wi (256 blocks) then Wo (256 blocks)
// blocks [8704,9472):   qkv pack (768 blocks = 48 sh x 16 D0)
// blocks [9472,9492):   bias canonicalization (5120 elems); block 9472 writes flag
// Dtype vote: ballot+popcount per wave (4 LDS atomics/block, not 256 serialized).
__global__ __launch_bounds__(256) void kprep(const void* __restrict__ x,
                                             const void* __restrict__ Wi, const void* __restrict__ Wo,
                                             const void* __restrict__ Wk, const void* __restrict__ Wq,
                                             const void* __restrict__ Wv,
                                             const void* __restrict__ bi, const void* __restrict__ bo,
                                             const void* __restrict__ bk, const void* __restrict__ bq,
                                             const void* __restrict__ bv,
                                             int* __restrict__ flag,
                                             float* __restrict__ bi_f, float* __restrict__ bo_f,
                                             float* __restrict__ bqkv_f,
                                             ushort* __restrict__ xh, ushort* __restrict__ WiT,
                                             ushort* __restrict__ WoT, ushort* __restrict__ WqkvT){
  __shared__ int cnt_s;
  __shared__ float tile[64][65];
  uint t = threadIdx.x, q = blockIdx.x;
  if (t == 0) cnt_s = 0;
  __syncthreads();
  {
    uint wv = ((const uint*)Wi)[t];
    uint e = (wv >> 7) & 0xFFu;
    unsigned long long mask = __ballot(e >= 100u && e <= 130u);
    if ((t & 63u) == 0u) atomicAdd(&cnt_s, __popcll(mask));
  }
  __syncthreads();
  int f = (cnt_s < 128) ? 1 : 0;

  if (q < 8192u){
    size_t g = (size_t)(q*256u + t)*8u;
    ushort o[8];
    if (f){
      const float4* xf = (const float4*)((const float*)x + g);
      float4 a = xf[0], b2 = xf[1];
      o[0] = f2h(a.x);  o[1] = f2h(a.y);  o[2] = f2h(a.z);  o[3] = f2h(a.w);
      o[4] = f2h(b2.x); o[5] = f2h(b2.y); o[6] = f2h(b2.z); o[7] = f2h(b2.w);
    } else {
      uint4 u = *(const uint4*)((const ushort*)x + g);
      ushort s[8];
      *(uint4*)s = u;
      #pragma unroll
      for (int i = 0; i < 8; ++i) o[i] = f2h(bf2f(s[i]));
    }
    *(uint4*)(xh + g) = *(uint4*)o;
  } else if (q < 8704u){
    uint qq = q - 8192u;
    const void* in = (qq < 256u) ? Wi : Wo;
    ushort* out = (qq < 256u) ? WiT : WoT;
    uint qi = qq & 255u;
    uint R0 = (qi & 15u)*64u, C0 = (qi >> 4)*64u;
    #pragma unroll
    for (int i = 0; i < 16; ++i){
      uint id = i*256u + t, r = id >> 6, c = id & 63u;
      tile[r][c] = ldf(in, (size_t)(R0 + r)*1024u + C0 + c, f);
    }
    __syncthreads();
    #pragma unroll
    for (int i = 0; i < 16; ++i){
      uint id = i*256u + t, r = id >> 6, c = id & 63u;   // r = out-row (C-dim)
      out[(size_t)(C0 + r)*1024u + R0 + c] = f2h(tile[c][r]);
    }
  } else if (q < 9472u){
    uint qq = q - 8704u;                 // [0,768)
    uint sh = qq % 48u, D0 = (qq / 48u)*64u;
    uint sel = sh >> 4, h = sh & 15u;
    const void* W = (sel == 0) ? Wk : ((sel == 1) ? Wq : Wv);
    #pragma unroll
    for (int i = 0; i < 16; ++i){
      uint id = i*256u + t, r = id >> 6, c = id & 63u;   // r = d-local, c = e
      tile[r][c] = ldf(W, (size_t)h*65536u + (size_t)(D0 + r)*64u + c, f);
    }
    __syncthreads();
    #pragma unroll
    for (int i = 0; i < 16; ++i){
      uint id = i*256u + t, r = id >> 6, c = id & 63u;   // r = e, c = d-local
      WqkvT[(size_t)(sel*1024u + h*64u + r)*1024u + D0 + c] = f2h(tile[c][r]);
    }
  } else {
    uint id = (q - 9472u)*256u + t;      // [0,5120)
    if (id < 1024u)       bi_f[id]         = ldf(bi, id, f);
    else if (id < 2048u)  bo_f[id - 1024u] = ldf(bo, id - 1024u, f);
    else {
      uint j = id - 2048u;               // [0,3072): sel*1024 + (h*64+e)
      uint sel = j >> 10, i = j & 1023u;
      const void* src = (sel == 0) ? bk : ((sel == 1) ? bq : bv);
      bqkv_f[j] = ldf(src, i, f);
    }
    if (q == 9472u && t == 0) flag[0] = f;
  }
}

// ---------------- GEMM: C[M,N] = A[M,K] @ Bt[N,K]^T + bias (fp16) ------------
// Double-buffered BK=32 K-loop (kattn's proven pattern): one barrier per iter;
// stage(t+1) issued right after the barrier, hidden under 16 MFMA + ds_reads
// of tile t, drained by the NEXT barrier. LDS 2x(8+8) = 32 KB -> 4 blocks/CU.
// Hazard: stage into buf^1 only overwrites data whose last ds_read completed
// before the barrier we just crossed (reads of buf^1 were in iter t-1).
// XOR-swizzled [128][32] tiles -> 2 lanes/16B-slot on frag reads (free).
// MODE 0: fp16 out [M,N].
// MODE 1: merged QKV epilogue: col<1024 -> k; 1024..2047 -> q * log2(e)
//         (folds softmax base-2 conversion before the single f2h rounding);
//         col>=2048 -> Vt scatter [(b,h,e)][s].
// MODE 2: final out, dtf picks f32/bf16.
template<int MODE>
__global__ __launch_bounds__(256, 4) void kgemm(const ushort* __restrict__ A, const ushort* __restrict__ Bt,
                                                const float* __restrict__ bias, void* __restrict__ Cv,
                                                ushort* __restrict__ Vt, const int* __restrict__ dtf,
                                                int M, int N, int K){
  __shared__ ushort sA[2][128*32];   // 2 x 8 KB
  __shared__ ushort sB[2][128*32];   // 2 x 8 KB
  uint tid = threadIdx.x, w = tid >> 6, lane = tid & 63u, quad = lane >> 4, l15 = lane & 15u;
  uint bm = blockIdx.x, bn = blockIdx.y;
  uint wm = w >> 1, wn = w & 1u;
  f32x4 acc[4][4] = {};

  const ushort* GA = A  + (size_t)(bm*128u)*(size_t)K;
  const ushort* GB = Bt + (size_t)(bn*128u)*(size_t)K;
  const int NK = K >> 5;

  stage32(GA, K, sA[0], tid);
  stage32(GB, K, sB[0], tid);

  for (int t = 0; t < NK; ++t){
    uint bu = (uint)t & 1u;
    __syncthreads();                       // drains stage into buf[bu] (+ prev reads)
    if (t + 1 < NK){                       // prefetch next half-tile pair
      stage32(GA + (size_t)(t + 1)*32u, K, sA[bu ^ 1u], tid);
      stage32(GB + (size_t)(t + 1)*32u, K, sB[bu ^ 1u], tid);
    }
    f16x8 aF[4], bF[4];
    #pragma unroll
    for (int i = 0; i < 4; ++i) aF[i] = ld16(swz32(sA[bu], wm*64u + (uint)i*16u + l15, quad));
    #pragma unroll
    for (int j = 0; j < 4; ++j) bF[j] = ld16(swz32(sB[bu], wn*64u + (uint)j*16u + l15, quad));
    #pragma unroll
    for (int i = 0; i < 4; ++i)
      #pragma unroll
      for (int j = 0; j < 4; ++j)
        acc[i][j] = __builtin_amdgcn_mfma_f32_16x16x32_f16(aF[i], bF[j], acc[i][j], 0, 0, 0);
  }

  int f32out = (MODE == 2) ? dtf[0] : 0;
  const float L2E = 1.44269504088896340736f;
  #pragma unroll
  for (int j = 0; j < 4; ++j){
    uint col = bn*128u + wn*64u + j*16u + l15;
    float bj = bias[col];
    #pragma unroll
    for (int i = 0; i < 4; ++i){
      uint row0 = bm*128u + wm*64u + i*16u + quad*4u;
      #pragma unroll
      for (int r = 0; r < 4; ++r){
        float val = acc[i][j][r] + bj;
        uint row = row0 + r;
        if (MODE == 0){
          ((ushort*)Cv)[(size_t)row*N + col] = f2h(val);
        } else if (MODE == 1){
          if (col < 1024u){
            ((ushort*)Cv)[(size_t)row*2048u + col] = f2h(val);
          } else if (col < 2048u){
            ((ushort*)Cv)[(size_t)row*2048u + col] = f2h(val * L2E);
          } else {
            uint c2 = col - 2048u;           // h*64+e ; row = b*512+s
            Vt[(size_t)(((row >> 9)*16u + (c2 >> 6))*64u + (c2 & 63u))*512u + (row & 511u)] = f2h(val);
          }
        } else {
          if (f32out) ((float*)Cv)[(size_t)row*N + col] = val;
          else        ((ushort*)Cv)[(size_t)row*N + col] = f2bf(val);
        }
      }
    }
  }
}

// ---------------- fused attention ("transposed" causal, flash-style) ---------
// S[t,s] = K[t,:]·Q[s,:], keep s<=t, softmax over s, O[t,:] = sum_s P[t,s]V[s,:]
// kq: fp16 [16384][2048] (q pre-scaled by log2e); Vt: fp16 [(b*16+h)*64+e][512]
// S is already in log2 domain -> exp2 directly.
// LPT: heavy (large tt) blocks launch first; light blocks backfill the tail.
// UNCHANGED this round (75 us, VALU-bound per R5 counters — next target).
__global__ __launch_bounds__(256, 4) void kattn(const ushort* __restrict__ kq,
                                                const ushort* __restrict__ Vt,
                                                ushort* __restrict__ Out){
  __shared__ ushort sQ[2][64*64];          // [s-local][d] swizzled   16 KB
  __shared__ ushort sV[2][64*64];          // [e][s-local] swizzled   16 KB
  __shared__ ushort pbuf[4][16*64];        // per-wave P (swizzled); K staging  8 KB
  uint tid = threadIdx.x, w = tid >> 6, lane = tid & 63u, quad = lane >> 4, l15 = lane & 15u;
  uint bh = blockIdx.x, tt = 7u - blockIdx.y;   // LPT: heavy tiles first
  uint b = bh >> 4, h = bh & 15u;
  uint t0 = tt*64u;
  const float MNEG = -1.0e30f;

  // stage K tile [t-local][d] into pbuf, Q0/V0 into buf 0 (all swizzled)
  stage64(kq + (size_t)(b*512u + t0)*2048u + h*64u, 2048u, (ushort*)pbuf, tid);
  stage64(kq + (size_t)(b*512u)*2048u + 1024u + h*64u, 2048u, sQ[0], tid);   // s0=0
  stage64(Vt + (size_t)(bh*64u)*512u, 512u, sV[0], tid);
  __syncthreads();

  f16x8 aK[2];  // K rows for this wave's 16 t's (wave-own pbuf rows)
  aK[0] = ld16(swz((const ushort*)pbuf, w*16u + l15, quad));
  aK[1] = ld16(swz((const ushort*)pbuf, w*16u + l15, 4u + quad));

  float m[4], l[4];
  f32x4 oacc[4];
  #pragma unroll
  for (int r = 0; r < 4; ++r){ m[r] = MNEG; l[r] = 0.f; }
  #pragma unroll
  for (int je = 0; je < 4; ++je) oacc[je] = (f32x4){0.f, 0.f, 0.f, 0.f};

  ushort* pw = (ushort*)pbuf + w*1024u;    // wave-private P region

  for (uint st = 0; st <= tt; ++st){
    uint cur = st & 1u;
    if (st) __syncthreads();               // staged bufs[cur] ready (vmcnt drained)
    if (st < tt){                          // prefetch st+1 with full-iter cover
      uint s1 = (st + 1u)*64u;
      stage64(kq + (size_t)(b*512u + s1)*2048u + 1024u + h*64u, 2048u, sQ[1u - cur], tid);
      stage64(Vt + (size_t)(bh*64u)*512u + s1, 512u, sV[1u - cur], tid);
    }
    f32x4 sacc[4];
    #pragma unroll
    for (int j = 0; j < 4; ++j){
      f16x8 bq0 = ld16(swz(sQ[cur], j*16u + l15, quad));
      f16x8 bq1 = ld16(swz(sQ[cur], j*16u + l15, 4u + quad));
      f32x4 s = (f32x4){0.f, 0.f, 0.f, 0.f};
      s = __builtin_amdgcn_mfma_f32_16x16x32_f16(aK[0], bq0, s, 0, 0, 0);
      s = __builtin_amdgcn_mfma_f32_16x16x32_f16(aK[1], bq1, s, 0, 0, 0);
      sacc[j] = s;
    }
    if (st == tt){  // diagonal tile: keep s<=t
      #pragma unroll
      for (int j = 0; j < 4; ++j)
        #pragma unroll
        for (int r = 0; r < 4; ++r)
          if (j*16u + l15 > w*16u + quad*4u + (uint)r) sacc[j][r] = MNEG;
    }
    float alpha[4];
    #pragma unroll
    for (int r = 0; r < 4; ++r){
      float v = fmaxf(fmaxf(sacc[0][r], sacc[1][r]), fmaxf(sacc[2][r], sacc[3][r]));
      v = fmaxf(v, __shfl_xor(v, 1));
      v = fmaxf(v, __shfl_xor(v, 2));
      v = fmaxf(v, __shfl_xor(v, 4));
      v = fmaxf(v, __shfl_xor(v, 8));
      float mn = fmaxf(m[r], v);
      alpha[r] = exp2f(m[r] - mn);         // already log2-domain
      m[r] = mn;
    }
    #pragma unroll
    for (int j = 0; j < 4; ++j)
      #pragma unroll
      for (int r = 0; r < 4; ++r)
        sacc[j][r] = exp2f(sacc[j][r] - m[r]);
    #pragma unroll
    for (int r = 0; r < 4; ++r){
      float s = sacc[0][r] + sacc[1][r] + sacc[2][r] + sacc[3][r];
      s += __shfl_xor(s, 1);
      s += __shfl_xor(s, 2);
      s += __shfl_xor(s, 4);
      s += __shfl_xor(s, 8);
      l[r] = l[r]*alpha[r] + s;
    }
    #pragma unroll
    for (int je = 0; je < 4; ++je)
      #pragma unroll
      for (int r = 0; r < 4; ++r)
        oacc[je][r] *= alpha[r];
    // P: C/D layout -> wave-private swizzled LDS -> A-operand frags (no barrier)
    #pragma unroll
    for (int j = 0; j < 4; ++j)
      #pragma unroll
      for (int r = 0; r < 4; ++r){
        uint t = quad*4u + (uint)r;
        pw[t*64u + (((j*2u + (l15 >> 3)) ^ (t & 7u))*8u) + (l15 & 7u)] = f2h(sacc[j][r]);
      }
    f16x8 aP0 = ld16(swz(pw, l15, quad));
    f16x8 aP1 = ld16(swz(pw, l15, 4u + quad));
    #pragma unroll
    for (int je = 0; je < 4; ++je){
      f16x8 bv0 = ld16(swz(sV[cur], je*16u + l15, quad));
      f16x8 bv1 = ld16(swz(sV[cur], je*16u + l15, 4u + quad));
      oacc[je] = __builtin_amdgcn_mfma_f32_16x16x32_f16(aP0, bv0, oacc[je], 0, 0, 0);
      oacc[je] = __builtin_amdgcn_mfma_f32_16x16x32_f16(aP1, bv1, oacc[je], 0, 0, 0);
    }
  }
  float inv[4];
  #pragma unroll
  for (int r = 0; r < 4; ++r) inv[r] = 1.0f / l[r];
  #pragma unroll
  for (int je = 0; je < 4; ++je){
    uint e = h*64u + je*16u + l15;
    #pragma unroll
    for (int r = 0; r < 4; ++r){
      uint t = t0 + w*16u + quad*4u + (uint)r;
      Out[(size_t)(b*512u + t)*1024u + e] = f2h(oacc[je][r]*inv[r]);
    }
  }
}

// ---------------- launcher ---------------------------------------------------

extern "C" void kernel_launch(void* const* d_in, const int* in_sizes, int n_in,
                              void* d_out, int out_size, void* d_ws, size_t ws_size,
                              hipStream_t stream){
  const void* x  = d_in[0];
  const void* Wi = d_in[1];
  const void* bi = d_in[2];
  const void* Wk = d_in[3];
  const void* bk = d_in[4];
  const void* Wq = d_in[5];
  const void* bq = d_in[6];
  const void* Wv = d_in[7];
  const void* bv = d_in[8];
  const void* Wo = d_in[9];
  const void* bo = d_in[10];
  char* ws = (char*)d_ws;

  const size_t MB = 1u << 20;
  int*    flag   = (int*)ws;
  float*  bi_f   = (float*)(ws + 4096);                  // 4 KB
  float*  bo_f   = (float*)(ws + 8192);                  // 4 KB
  float*  bqkv_f = (float*)(ws + 12288);                 // 12 KB
  ushort* WiT    = (ushort*)(ws + 32768);                // 2 MB  (fp16)
  ushort* WoT    = (ushort*)(ws + 32768 + 2*MB);         // 2 MB
  ushort* WqkvT  = (ushort*)(ws + 32768 + 4*MB);         // 6 MB
  ushort* xh     = (ushort*)(ws + 32768 + 10*MB);        // 32 MB (dead after GEMM0)
  ushort* kq     = (ushort*)(ws + 32768 + 10*MB);        // 64 MB (overlays xh)
  ushort* hbuf   = (ushort*)(ws + 32768 + 74*MB);        // 32 MB (h, then attn out)
  ushort* Vt     = (ushort*)(ws + 32768 + 106*MB);       // 32 MB -> total ~138 MB

  kprep<<<dim3(9492), dim3(256), 0, stream>>>(x, Wi, Wo, Wk, Wq, Wv, bi, bo, bk, bq, bv,
                                              flag, bi_f, bo_f, bqkv_f, xh, WiT, WoT, WqkvT);

  kgemm<0><<<dim3(128, 8),  dim3(256), 0, stream>>>(xh,   WiT,   bi_f,   hbuf,  nullptr, nullptr, NTOK, 1024, 1024);
  kgemm<1><<<dim3(128, 24), dim3(256), 0, stream>>>(hbuf, WqkvT, bqkv_f, kq,    Vt,      nullptr, NTOK, 3072, 1024);
  kattn<<<dim3(512, 8), dim3(256), 0, stream>>>(kq, Vt, hbuf);
  kgemm<2><<<dim3(128, 8),  dim3(256), 0, stream>>>(hbuf, WoT,   bo_f,   d_out, nullptr, flag,   NTOK, 1024, 1024);
}

// Round 7
// 451.812 us; speedup vs baseline: 1.0616x; 1.0616x over previous
//
#include <hip/hip_runtime.h>
#include <hip/hip_bf16.h>
#include <stdint.h>

// B=32, T=512, D=1024, H=16, HD=64
#define NTOK 16384

typedef _Float16 f16;
typedef f16   f16x8 __attribute__((ext_vector_type(8)));
typedef float f32x4 __attribute__((ext_vector_type(4)));

__device__ __forceinline__ float bf2f(ushort h){
  union { uint32_t u; float f; } v; v.u = ((uint32_t)h) << 16; return v.f;
}
__device__ __forceinline__ ushort f2bf(float f){
  union { float f; uint32_t u; } v; v.f = f;
  uint32_t u = v.u;
  return (ushort)((u + 0x7FFFu + ((u >> 16) & 1u)) >> 16);  // RNE
}
__device__ __forceinline__ ushort f2h(float f){          // fp32 -> fp16 bits (RNE)
  return __builtin_bit_cast(ushort, (f16)f);
}
__device__ __forceinline__ f16x8 ld16(const ushort* p){  // 8 fp16
  uint4 u = *(const uint4*)p;
  return __builtin_bit_cast(f16x8, u);
}
// dtype-flexible fp32 load: fp32 path direct, bf16 path converts
__device__ __forceinline__ float ldf(const void* p, size_t idx, int isf32){
  if (isf32) return ((const float*)p)[idx];
  return bf2f(((const ushort*)p)[idx]);
}

// XOR-swizzled [*][64] fp16 tile in LDS: element (row,col) lives at
//   row*64 + ((col>>3) ^ (row&7))*8 + (col&7)
// -> b128 fragment reads hit 8 distinct bank groups instead of serializing.
__device__ __forceinline__ const ushort* swz(const ushort* base, uint row, uint chunk){
  return base + (size_t)row*64u + (size_t)((chunk ^ (row & 7u))*8u);
}

// stage a 64x64 fp16 tile (row stride strideEl) into swizzled LDS via
// global_load_lds width-16. Dest chunk is wave-uniform-base + lane*16B; the
// SOURCE chunk is permuted with the same involution (both-sides rule).
__device__ __forceinline__ void stage64(const ushort* g, uint strideEl,
                                        ushort* ldsbase, uint tid){
  uint w = tid >> 6;
  #pragma unroll
  for (int i = 0; i < 2; ++i){
    uint lc  = i*256u + tid;               // dest chunk id (16B units)
    uint row = lc >> 3, cp = lc & 7u;
    uint c   = cp ^ (row & 7u);            // swizzled source chunk
    const ushort* gp = g + (size_t)row*strideEl + c*8u;
    ushort* lp = ldsbase + (size_t)(i*256u + w*64u)*8u;   // wave-uniform base
    __builtin_amdgcn_global_load_lds((const __attribute__((address_space(1))) void*)gp,
        (__attribute__((address_space(3))) void*)lp, 16, 0, 0);
  }
}

// stage a 128x64 fp16 tile (row stride K) into swizzled LDS (GEMM staging).
__device__ __forceinline__ void stage128(const ushort* g, int K,
                                         ushort* ldsbase, uint tid){
  uint w = tid >> 6;
  #pragma unroll
  for (int i = 0; i < 4; ++i){
    uint lc  = i*256u + tid;               // dest chunk id in [0,1024)
    uint row = lc >> 3, cp = lc & 7u;
    uint c   = cp ^ (row & 7u);            // swizzled source chunk
    const ushort* gp = g + (size_t)row*(size_t)K + c*8u;
    ushort* lp = ldsbase + (size_t)(i*256u + w*64u)*8u;   // wave-uniform base
    __builtin_amdgcn_global_load_lds((const __attribute__((address_space(1))) void*)gp,
        (__attribute__((address_space(3))) void*)lp, 16, 0, 0);
  }
}

// ---------------- merged preprocessing (one dispatch) -------------------------
// blocks [0,8192):      x -> canonical fp16 (8 elems/thread)
// blocks [8192,8704):   transpose Wi (256 blocks) then Wo (256 blocks)
// blocks [8704,9472):   qkv pack (768 blocks = 48 sh x 16 D0)
// blocks [9472,9492):   bias canonicalization (5120 elems); block 9472 writes flag
// Dtype vote: ballot+popcount per wave (4 LDS atomics/block).
__global__ __launch_bounds__(256) void kprep(const void* __restrict__ x,
                                             const void* __restrict__ Wi, const void* __restrict__ Wo,
                                             const void* __restrict__ Wk, const void* __restrict__ Wq,
                                             const void* __restrict__ Wv,
                                             const void* __restrict__ bi, const void* __restrict__ bo,
                                             const void* __restrict__ bk, const void* __restrict__ bq,
                                             const void* __restrict__ bv,
                                             int* __restrict__ flag,
                                             float* __restrict__ bi_f, float* __restrict__ bo_f,
                                             float* __restrict__ bqkv_f,
                                             ushort* __restrict__ xh, ushort* __restrict__ WiT,
                                             ushort* __restrict__ WoT, ushort* __restrict__ WqkvT){
  __shared__ int cnt_s;
  __shared__ float tile[64][65];
  uint t = threadIdx.x, q = blockIdx.x;
  if (t == 0) cnt_s = 0;
  __syncthreads();
  {
    uint wv = ((const uint*)Wi)[t];
    uint e = (wv >> 7) & 0xFFu;
    unsigned long long mask = __ballot(e >= 100u && e <= 130u);
    if ((t & 63u) == 0u) atomicAdd(&cnt_s, __popcll(mask));
  }
  __syncthreads();
  int f = (cnt_s < 128) ? 1 : 0;

  if (q < 8192u){
    size_t g = (size_t)(q*256u + t)*8u;
    ushort o[8];
    if (f){
      const float4* xf = (const float4*)((const float*)x + g);
      float4 a = xf[0], b2 = xf[1];
      o[0] = f2h(a.x);  o[1] = f2h(a.y);  o[2] = f2h(a.z);  o[3] = f2h(a.w);
      o[4] = f2h(b2.x); o[5] = f2h(b2.y); o[6] = f2h(b2.z); o[7] = f2h(b2.w);
    } else {
      uint4 u = *(const uint4*)((const ushort*)x + g);
      ushort s[8];
      *(uint4*)s = u;
      #pragma unroll
      for (int i = 0; i < 8; ++i) o[i] = f2h(bf2f(s[i]));
    }
    *(uint4*)(xh + g) = *(uint4*)o;
  } else if (q < 8704u){
    uint qq = q - 8192u;
    const void* in = (qq < 256u) ? Wi : Wo;
    ushort* out = (qq < 256u) ? WiT : WoT;
    uint qi = qq & 255u;
    uint R0 = (qi & 15u)*64u, C0 = (qi >> 4)*64u;
    #pragma unroll
    for (int i = 0; i < 16; ++i){
      uint id = i*256u + t, r = id >> 6, c = id & 63u;
      tile[r][c] = ldf(in, (size_t)(R0 + r)*1024u + C0 + c, f);
    }
    __syncthreads();
    #pragma unroll
    for (int i = 0; i < 16; ++i){
      uint id = i*256u + t, r = id >> 6, c = id & 63u;   // r = out-row (C-dim)
      out[(size_t)(C0 + r)*1024u + R0 + c] = f2h(tile[c][r]);
    }
  } else if (q < 9472u){
    uint qq = q - 8704u;                 // [0,768)
    uint sh = qq % 48u, D0 = (qq / 48u)*64u;
    uint sel = sh >> 4, h = sh & 15u;
    const void* W = (sel == 0) ? Wk : ((sel == 1) ? Wq : Wv);
    #pragma unroll
    for (int i = 0; i < 16; ++i){
      uint id = i*256u + t, r = id >> 6, c = id & 63u;   // r = d-local, c = e
      tile[r][c] = ldf(W, (size_t)h*65536u + (size_t)(D0 + r)*64u + c, f);
    }
    __syncthreads();
    #pragma unroll
    for (int i = 0; i < 16; ++i){
      uint id = i*256u + t, r = id >> 6, c = id & 63u;   // r = e, c = d-local
      WqkvT[(size_t)(sel*1024u + h*64u + r)*1024u + D0 + c] = f2h(tile[c][r]);
    }
  } else {
    uint id = (q - 9472u)*256u + t;      // [0,5120)
    if (id < 1024u)       bi_f[id]         = ldf(bi, id, f);
    else if (id < 2048u)  bo_f[id - 1024u] = ldf(bo, id - 1024u, f);
    else {
      uint j = id - 2048u;               // [0,3072): sel*1024 + (h*64+e)
      uint sel = j >> 10, i = j & 1023u;
      const void* src = (sel == 0) ? bk : ((sel == 1) ? bq : bv);
      bqkv_f[j] = ldf(src, i, f);
    }
    if (q == 9472u && t == 0) flag[0] = f;
  }
}

// ---------------- GEMM: C[M,N] = A[M,K] @ Bt[N,K]^T + bias (fp16) ------------
// R4's proven config: BK=64 (32 MFMA per barrier-pair), XOR-swizzled [128][64]
// LDS tiles (source pre-swizzle + swizzled read -> conflicts = 0, 840 TF).
// LDS 32 KB -> 4 blocks/CU with launch_bounds(256,4).
// MODE 0: fp16 out [M,N].
// MODE 1: merged QKV epilogue: col<1024 -> k; 1024..2047 -> q * log2(e)
//         (folds softmax base-2 conversion before the single f2h rounding);
//         col>=2048 -> Vt scatter [(b,h,e)][s].
// MODE 2: final out, dtf picks f32/bf16.
template<int MODE>
__global__ __launch_bounds__(256, 4) void kgemm(const ushort* __restrict__ A, const ushort* __restrict__ Bt,
                                                const float* __restrict__ bias, void* __restrict__ Cv,
                                                ushort* __restrict__ Vt, const int* __restrict__ dtf,
                                                int M, int N, int K){
  __shared__ ushort sA[128*64];   // 16 KB, swizzled
  __shared__ ushort sB[128*64];   // 16 KB, swizzled
  uint tid = threadIdx.x, w = tid >> 6, lane = tid & 63u, quad = lane >> 4, l15 = lane & 15u;
  uint bm = blockIdx.x, bn = blockIdx.y;
  uint wm = w >> 1, wn = w & 1u;
  f32x4 acc[4][4] = {};

  for (int k0 = 0; k0 < K; k0 += 64){
    stage128(A  + (size_t)(bm*128u)*(size_t)K + k0, K, sA, tid);
    stage128(Bt + (size_t)(bn*128u)*(size_t)K + k0, K, sB, tid);
    __syncthreads();
    #pragma unroll
    for (int kk = 0; kk < 2; ++kk){
      f16x8 aF[4], bF[4];
      #pragma unroll
      for (int i = 0; i < 4; ++i) aF[i] = ld16(swz(sA, wm*64u + (uint)i*16u + l15, (uint)kk*4u + quad));
      #pragma unroll
      for (int j = 0; j < 4; ++j) bF[j] = ld16(swz(sB, wn*64u + (uint)j*16u + l15, (uint)kk*4u + quad));
      #pragma unroll
      for (int i = 0; i < 4; ++i)
        #pragma unroll
        for (int j = 0; j < 4; ++j)
          acc[i][j] = __builtin_amdgcn_mfma_f32_16x16x32_f16(aF[i], bF[j], acc[i][j], 0, 0, 0);
    }
    __syncthreads();
  }
  int f32out = (MODE == 2) ? dtf[0] : 0;
  const float L2E = 1.44269504088896340736f;
  #pragma unroll
  for (int j = 0; j < 4; ++j){
    uint col = bn*128u + wn*64u + j*16u + l15;
    float bj = bias[col];
    #pragma unroll
    for (int i = 0; i < 4; ++i){
      uint row0 = bm*128u + wm*64u + i*16u + quad*4u;
      #pragma unroll
      for (int r = 0; r < 4; ++r){
        float val = acc[i][j][r] + bj;
        uint row = row0 + r;
        if (MODE == 0){
          ((ushort*)Cv)[(size_t)row*N + col] = f2h(val);
        } else if (MODE == 1){
          if (col < 1024u){
            ((ushort*)Cv)[(size_t)row*2048u + col] = f2h(val);
          } else if (col < 2048u){
            ((ushort*)Cv)[(size_t)row*2048u + col] = f2h(val * L2E);
          } else {
            uint c2 = col - 2048u;           // h*64+e ; row = b*512+s
            Vt[(size_t)(((row >> 9)*16u + (c2 >> 6))*64u + (c2 & 63u))*512u + (row & 511u)] = f2h(val);
          }
        } else {
          if (f32out) ((float*)Cv)[(size_t)row*N + col] = val;
          else        ((ushort*)Cv)[(size_t)row*N + col] = f2bf(val);
        }
      }
    }
  }
}

// ---------------- fused attention ("transposed" causal, flash-style) ---------
// S[t,s] = K[t,:]·Q[s,:], keep s<=t, softmax over s, O[t,:] = sum_s P[t,s]V[s,:]
// kq: fp16 [16384][2048] (q pre-scaled by log2e); Vt: fp16 [(b*16+h)*64+e][512]
// S is already in log2 domain -> exp2 directly.
// LPT: heavy (large tt) blocks launch first; light blocks backfill the tail.
// UNCHANGED (75 us, mixed VALU/latency-bound — GEMM+dispatch overhead first).
__global__ __launch_bounds__(256, 4) void kattn(const ushort* __restrict__ kq,
                                                const ushort* __restrict__ Vt,
                                                ushort* __restrict__ Out){
  __shared__ ushort sQ[2][64*64];          // [s-local][d] swizzled   16 KB
  __shared__ ushort sV[2][64*64];          // [e][s-local] swizzled   16 KB
  __shared__ ushort pbuf[4][16*64];        // per-wave P (swizzled); K staging  8 KB
  uint tid = threadIdx.x, w = tid >> 6, lane = tid & 63u, quad = lane >> 4, l15 = lane & 15u;
  uint bh = blockIdx.x, tt = 7u - blockIdx.y;   // LPT: heavy tiles first
  uint b = bh >> 4, h = bh & 15u;
  uint t0 = tt*64u;
  const float MNEG = -1.0e30f;

  // stage K tile [t-local][d] into pbuf, Q0/V0 into buf 0 (all swizzled)
  stage64(kq + (size_t)(b*512u + t0)*2048u + h*64u, 2048u, (ushort*)pbuf, tid);
  stage64(kq + (size_t)(b*512u)*2048u + 1024u + h*64u, 2048u, sQ[0], tid);   // s0=0
  stage64(Vt + (size_t)(bh*64u)*512u, 512u, sV[0], tid);
  __syncthreads();

  f16x8 aK[2];  // K rows for this wave's 16 t's (wave-own pbuf rows)
  aK[0] = ld16(swz((const ushort*)pbuf, w*16u + l15, quad));
  aK[1] = ld16(swz((const ushort*)pbuf, w*16u + l15, 4u + quad));

  float m[4], l[4];
  f32x4 oacc[4];
  #pragma unroll
  for (int r = 0; r < 4; ++r){ m[r] = MNEG; l[r] = 0.f; }
  #pragma unroll
  for (int je = 0; je < 4; ++je) oacc[je] = (f32x4){0.f, 0.f, 0.f, 0.f};

  ushort* pw = (ushort*)pbuf + w*1024u;    // wave-private P region

  for (uint st = 0; st <= tt; ++st){
    uint cur = st & 1u;
    if (st) __syncthreads();               // staged bufs[cur] ready (vmcnt drained)
    if (st < tt){                          // prefetch st+1 with full-iter cover
      uint s1 = (st + 1u)*64u;
      stage64(kq + (size_t)(b*512u + s1)*2048u + 1024u + h*64u, 2048u, sQ[1u - cur], tid);
      stage64(Vt + (size_t)(bh*64u)*512u + s1, 512u, sV[1u - cur], tid);
    }
    f32x4 sacc[4];
    #pragma unroll
    for (int j = 0; j < 4; ++j){
      f16x8 bq0 = ld16(swz(sQ[cur], j*16u + l15, quad));
      f16x8 bq1 = ld16(swz(sQ[cur], j*16u + l15, 4u + quad));
      f32x4 s = (f32x4){0.f, 0.f, 0.f, 0.f};
      s = __builtin_amdgcn_mfma_f32_16x16x32_f16(aK[0], bq0, s, 0, 0, 0);
      s = __builtin_amdgcn_mfma_f32_16x16x32_f16(aK[1], bq1, s, 0, 0, 0);
      sacc[j] = s;
    }
    if (st == tt){  // diagonal tile: keep s<=t
      #pragma unroll
      for (int j = 0; j < 4; ++j)
        #pragma unroll
        for (int r = 0; r < 4; ++r)
          if (j*16u + l15 > w*16u + quad*4u + (uint)r) sacc[j][r] = MNEG;
    }
    float alpha[4];
    #pragma unroll
    for (int r = 0; r < 4; ++r){
      float v = fmaxf(fmaxf(sacc[0][r], sacc[1][r]), fmaxf(sacc[2][r], sacc[3][r]));
      v = fmaxf(v, __shfl_xor(v, 1));
      v = fmaxf(v, __shfl_xor(v, 2));
      v = fmaxf(v, __shfl_xor(v, 4));
      v = fmaxf(v, __shfl_xor(v, 8));
      float mn = fmaxf(m[r], v);
      alpha[r] = exp2f(m[r] - mn);         // already log2-domain
      m[r] = mn;
    }
    #pragma unroll
    for (int j = 0; j < 4; ++j)
      #pragma unroll
      for (int r = 0; r < 4; ++r)
        sacc[j][r] = exp2f(sacc[j][r] - m[r]);
    #pragma unroll
    for (int r = 0; r < 4; ++r){
      float s = sacc[0][r] + sacc[1][r] + sacc[2][r] + sacc[3][r];
      s += __shfl_xor(s, 1);
      s += __shfl_xor(s, 2);
      s += __shfl_xor(s, 4);
      s += __shfl_xor(s, 8);
      l[r] = l[r]*alpha[r] + s;
    }
    #pragma unroll
    for (int je = 0; je < 4; ++je)
      #pragma unroll
      for (int r = 0; r < 4; ++r)
        oacc[je][r] *= alpha[r];
    // P: C/D layout -> wave-private swizzled LDS -> A-operand frags (no barrier)
    #pragma unroll
    for (int j = 0; j < 4; ++j)
      #pragma unroll
      for (int r = 0; r < 4; ++r){
        uint t = quad*4u + (uint)r;
        pw[t*64u + (((j*2u + (l15 >> 3)) ^ (t & 7u))*8u) + (l15 & 7u)] = f2h(sacc[j][r]);
      }
    f16x8 aP0 = ld16(swz(pw, l15, quad));
    f16x8 aP1 = ld16(swz(pw, l15, 4u + quad));
    #pragma unroll
    for (int je = 0; je < 4; ++je){
      f16x8 bv0 = ld16(swz(sV[cur], je*16u + l15, quad));
      f16x8 bv1 = ld16(swz(sV[cur], je*16u + l15, 4u + quad));
      oacc[je] = __builtin_amdgcn_mfma_f32_16x16x32_f16(aP0, bv0, oacc[je], 0, 0, 0);
      oacc[je] = __builtin_amdgcn_mfma_f32_16x16x32_f16(aP1, bv1, oacc[je], 0, 0, 0);
    }
  }
  float inv[4];
  #pragma unroll
  for (int r = 0; r < 4; ++r) inv[r] = 1.0f / l[r];
  #pragma unroll
  for (int je = 0; je < 4; ++je){
    uint e = h*64u + je*16u + l15;
    #pragma unroll
    for (int r = 0; r < 4; ++r){
      uint t = t0 + w*16u + quad*4u + (uint)r;
      Out[(size_t)(b*512u + t)*1024u + e] = f2h(oacc[je][r]*inv[r]);
    }
  }
}

// ---------------- launcher ---------------------------------------------------

extern "C" void kernel_launch(void* const* d_in, const int* in_sizes, int n_in,
                              void* d_out, int out_size, void* d_ws, size_t ws_size,
                              hipStream_t stream){
  const void* x  = d_in[0];
  const void* Wi = d_in[1];
  const void* bi = d_in[2];
  const void* Wk = d_in[3];
  const void* bk = d_in[4];
  const void* Wq = d_in[5];
  const void* bq = d_in[6];
  const void* Wv = d_in[7];
  const void* bv = d_in[8];
  const void* Wo = d_in[9];
  const void* bo = d_in[10];
  char* ws = (char*)d_ws;

  const size_t MB = 1u << 20;
  int*    flag   = (int*)ws;
  float*  bi_f   = (float*)(ws + 4096);                  // 4 KB
  float*  bo_f   = (float*)(ws + 8192);                  // 4 KB
  float*  bqkv_f = (float*)(ws + 12288);                 // 12 KB
  ushort* WiT    = (ushort*)(ws + 32768);                // 2 MB  (fp16)
  ushort* WoT    = (ushort*)(ws + 32768 + 2*MB);         // 2 MB
  ushort* WqkvT  = (ushort*)(ws + 32768 + 4*MB);         // 6 MB
  ushort* xh     = (ushort*)(ws + 32768 + 10*MB);        // 32 MB (dead after GEMM0)
  ushort* kq     = (ushort*)(ws + 32768 + 10*MB);        // 64 MB (overlays xh)
  ushort* hbuf   = (ushort*)(ws + 32768 + 74*MB);        // 32 MB (h, then attn out)
  ushort* Vt     = (ushort*)(ws + 32768 + 106*MB);       // 32 MB -> total ~138 MB

  kprep<<<dim3(9492), dim3(256), 0, stream>>>(x, Wi, Wo, Wk, Wq, Wv, bi, bo, bk, bq, bv,
                                              flag, bi_f, bo_f, bqkv_f, xh, WiT, WoT, WqkvT);

  kgemm<0><<<dim3(128, 8),  dim3(256), 0, stream>>>(xh,   WiT,   bi_f,   hbuf,  nullptr, nullptr, NTOK, 1024, 1024);
  kgemm<1><<<dim3(128, 24), dim3(256), 0, stream>>>(hbuf, WqkvT, bqkv_f, kq,    Vt,      nullptr, NTOK, 3072, 1024);
  kattn<<<dim3(512, 8), dim3(256), 0, stream>>>(kq, Vt, hbuf);
  kgemm<2><<<dim3(128, 8),  dim3(256), 0, stream>>>(hbuf, WoT,   bo_f,   d_out, nullptr, flag,   NTOK, 1024, 1024);
}

// Round 8
// 432.003 us; speedup vs baseline: 1.1103x; 1.0459x over previous
//
#include <hip/hip_runtime.h>
#include <hip/hip_bf16.h>
#include <stdint.h>

// B=32, T=512, D=1024, H=16, HD=64
#define NTOK 16384

typedef _Float16 f16;
typedef f16   f16x8 __attribute__((ext_vector_type(8)));
typedef float f32x4 __attribute__((ext_vector_type(4)));

__device__ __forceinline__ float bf2f(ushort h){
  union { uint32_t u; float f; } v; v.u = ((uint32_t)h) << 16; return v.f;
}
__device__ __forceinline__ ushort f2bf(float f){
  union { float f; uint32_t u; } v; v.f = f;
  uint32_t u = v.u;
  return (ushort)((u + 0x7FFFu + ((u >> 16) & 1u)) >> 16);  // RNE
}
__device__ __forceinline__ ushort f2h(float f){          // fp32 -> fp16 bits (RNE)
  return __builtin_bit_cast(ushort, (f16)f);
}
__device__ __forceinline__ f16x8 ld16(const ushort* p){  // 8 fp16
  uint4 u = *(const uint4*)p;
  return __builtin_bit_cast(f16x8, u);
}
// dtype-flexible fp32 load: fp32 path direct, bf16 path converts
__device__ __forceinline__ float ldf(const void* p, size_t idx, int isf32){
  if (isf32) return ((const float*)p)[idx];
  return bf2f(((const ushort*)p)[idx]);
}

// XOR-swizzled [*][64] fp16 tile in LDS: element (row,col) lives at
//   row*64 + ((col>>3) ^ (row&7))*8 + (col&7)
// -> b128 fragment reads hit 8 distinct bank groups instead of serializing.
__device__ __forceinline__ const ushort* swz(const ushort* base, uint row, uint chunk){
  return base + (size_t)row*64u + (size_t)((chunk ^ (row & 7u))*8u);
}

// stage a 64x64 fp16 tile (row stride strideEl) into swizzled LDS via
// global_load_lds width-16. Dest chunk is wave-uniform-base + lane*16B; the
// SOURCE chunk is permuted with the same involution (both-sides rule).
__device__ __forceinline__ void stage64(const ushort* g, uint strideEl,
                                        ushort* ldsbase, uint tid){
  uint w = tid >> 6;
  #pragma unroll
  for (int i = 0; i < 2; ++i){
    uint lc  = i*256u + tid;               // dest chunk id (16B units)
    uint row = lc >> 3, cp = lc & 7u;
    uint c   = cp ^ (row & 7u);            // swizzled source chunk
    const ushort* gp = g + (size_t)row*strideEl + c*8u;
    ushort* lp = ldsbase + (size_t)(i*256u + w*64u)*8u;   // wave-uniform base
    __builtin_amdgcn_global_load_lds((const __attribute__((address_space(1))) void*)gp,
        (__attribute__((address_space(3))) void*)lp, 16, 0, 0);
  }
}

// stage a 128x64 fp16 tile (row stride K) into swizzled LDS (GEMM staging).
__device__ __forceinline__ void stage128(const ushort* g, int K,
                                         ushort* ldsbase, uint tid){
  uint w = tid >> 6;
  #pragma unroll
  for (int i = 0; i < 4; ++i){
    uint lc  = i*256u + tid;               // dest chunk id in [0,1024)
    uint row = lc >> 3, cp = lc & 7u;
    uint c   = cp ^ (row & 7u);            // swizzled source chunk
    const ushort* gp = g + (size_t)row*(size_t)K + c*8u;
    ushort* lp = ldsbase + (size_t)(i*256u + w*64u)*8u;   // wave-uniform base
    __builtin_amdgcn_global_load_lds((const __attribute__((address_space(1))) void*)gp,
        (__attribute__((address_space(3))) void*)lp, 16, 0, 0);
  }
}

// ---------------- merged preprocessing (one dispatch) -------------------------
// blocks [0,8192):      x -> canonical fp16 (8 elems/thread)
// blocks [8192,8704):   transpose Wi (256 blocks) then Wo (256 blocks)
// blocks [8704,9472):   qkv pack (768 blocks = 48 sh x 16 D0)
// blocks [9472,9492):   bias canonicalization (5120 elems); block 9472 writes flag
// Dtype vote: ballot+popcount per wave (4 LDS atomics/block).
__global__ __launch_bounds__(256) void kprep(const void* __restrict__ x,
                                             const void* __restrict__ Wi, const void* __restrict__ Wo,
                                             const void* __restrict__ Wk, const void* __restrict__ Wq,
                                             const void* __restrict__ Wv,
                                             const void* __restrict__ bi, const void* __restrict__ bo,
                                             const void* __restrict__ bk, const void* __restrict__ bq,
                                             const void* __restrict__ bv,
                                             int* __restrict__ flag,
                                             float* __restrict__ bi_f, float* __restrict__ bo_f,
                                             float* __restrict__ bqkv_f,
                                             ushort* __restrict__ xh, ushort* __restrict__ WiT,
                                             ushort* __restrict__ WoT, ushort* __restrict__ WqkvT){
  __shared__ int cnt_s;
  __shared__ float tile[64][65];
  uint t = threadIdx.x, q = blockIdx.x;
  if (t == 0) cnt_s = 0;
  __syncthreads();
  {
    uint wv = ((const uint*)Wi)[t];
    uint e = (wv >> 7) & 0xFFu;
    unsigned long long mask = __ballot(e >= 100u && e <= 130u);
    if ((t & 63u) == 0u) atomicAdd(&cnt_s, __popcll(mask));
  }
  __syncthreads();
  int f = (cnt_s < 128) ? 1 : 0;

  if (q < 8192u){
    size_t g = (size_t)(q*256u + t)*8u;
    ushort o[8];
    if (f){
      const float4* xf = (const float4*)((const float*)x + g);
      float4 a = xf[0], b2 = xf[1];
      o[0] = f2h(a.x);  o[1] = f2h(a.y);  o[2] = f2h(a.z);  o[3] = f2h(a.w);
      o[4] = f2h(b2.x); o[5] = f2h(b2.y); o[6] = f2h(b2.z); o[7] = f2h(b2.w);
    } else {
      uint4 u = *(const uint4*)((const ushort*)x + g);
      ushort s[8];
      *(uint4*)s = u;
      #pragma unroll
      for (int i = 0; i < 8; ++i) o[i] = f2h(bf2f(s[i]));
    }
    *(uint4*)(xh + g) = *(uint4*)o;
  } else if (q < 8704u){
    uint qq = q - 8192u;
    const void* in = (qq < 256u) ? Wi : Wo;
    ushort* out = (qq < 256u) ? WiT : WoT;
    uint qi = qq & 255u;
    uint R0 = (qi & 15u)*64u, C0 = (qi >> 4)*64u;
    #pragma unroll
    for (int i = 0; i < 16; ++i){
      uint id = i*256u + t, r = id >> 6, c = id & 63u;
      tile[r][c] = ldf(in, (size_t)(R0 + r)*1024u + C0 + c, f);
    }
    __syncthreads();
    #pragma unroll
    for (int i = 0; i < 16; ++i){
      uint id = i*256u + t, r = id >> 6, c = id & 63u;   // r = out-row (C-dim)
      out[(size_t)(C0 + r)*1024u + R0 + c] = f2h(tile[c][r]);
    }
  } else if (q < 9472u){
    uint qq = q - 8704u;                 // [0,768)
    uint sh = qq % 48u, D0 = (qq / 48u)*64u;
    uint sel = sh >> 4, h = sh & 15u;
    const void* W = (sel == 0) ? Wk : ((sel == 1) ? Wq : Wv);
    #pragma unroll
    for (int i = 0; i < 16; ++i){
      uint id = i*256u + t, r = id >> 6, c = id & 63u;   // r = d-local, c = e
      tile[r][c] = ldf(W, (size_t)h*65536u + (size_t)(D0 + r)*64u + c, f);
    }
    __syncthreads();
    #pragma unroll
    for (int i = 0; i < 16; ++i){
      uint id = i*256u + t, r = id >> 6, c = id & 63u;   // r = e, c = d-local
      WqkvT[(size_t)(sel*1024u + h*64u + r)*1024u + D0 + c] = f2h(tile[c][r]);
    }
  } else {
    uint id = (q - 9472u)*256u + t;      // [0,5120)
    if (id < 1024u)       bi_f[id]         = ldf(bi, id, f);
    else if (id < 2048u)  bo_f[id - 1024u] = ldf(bo, id - 1024u, f);
    else {
      uint j = id - 2048u;               // [0,3072): sel*1024 + (h*64+e)
      uint sel = j >> 10, i = j & 1023u;
      const void* src = (sel == 0) ? bk : ((sel == 1) ? bq : bv);
      bqkv_f[j] = ldf(src, i, f);
    }
    if (q == 9472u && t == 0) flag[0] = f;
  }
}

// ---------------- GEMM: C[M,N] = A[M,K] @ Bt[N,K]^T + bias (fp16) ------------
// Proven config (R4/R5): BK=64 (32 MFMA per barrier-pair), XOR-swizzled
// [128][64] LDS tiles (source pre-swizzle + swizzled read -> conflicts = 0).
// LDS 32 KB -> 4 blocks/CU with launch_bounds(256,4).
// MODE 0: fp16 out [M,N].   MODE 2: final out, dtf picks f32/bf16.
// MODE 3: kq half-out [M,2048] at column base cb; q-half (cb!=0) pre-scaled by
//         log2(e) in f32 before the single f2h rounding (folds softmax base-2).
// MODE 4: V out, col = h*64+e in [0,1024) -> Vt scatter [(b,h,e)][s].
template<int MODE>
__global__ __launch_bounds__(256, 4) void kgemm(const ushort* __restrict__ A, const ushort* __restrict__ Bt,
                                                const float* __restrict__ bias, void* __restrict__ Cv,
                                                ushort* __restrict__ Vt, const int* __restrict__ dtf,
                                                int M, int N, int K, int cb){
  __shared__ ushort sA[128*64];   // 16 KB, swizzled
  __shared__ ushort sB[128*64];   // 16 KB, swizzled
  uint tid = threadIdx.x, w = tid >> 6, lane = tid & 63u, quad = lane >> 4, l15 = lane & 15u;
  uint bm = blockIdx.x, bn = blockIdx.y;
  uint wm = w >> 1, wn = w & 1u;
  f32x4 acc[4][4] = {};

  for (int k0 = 0; k0 < K; k0 += 64){
    stage128(A  + (size_t)(bm*128u)*(size_t)K + k0, K, sA, tid);
    stage128(Bt + (size_t)(bn*128u)*(size_t)K + k0, K, sB, tid);
    __syncthreads();
    #pragma unroll
    for (int kk = 0; kk < 2; ++kk){
      f16x8 aF[4], bF[4];
      #pragma unroll
      for (int i = 0; i < 4; ++i) aF[i] = ld16(swz(sA, wm*64u + (uint)i*16u + l15, (uint)kk*4u + quad));
      #pragma unroll
      for (int j = 0; j < 4; ++j) bF[j] = ld16(swz(sB, wn*64u + (uint)j*16u + l15, (uint)kk*4u + quad));
      #pragma unroll
      for (int i = 0; i < 4; ++i)
        #pragma unroll
        for (int j = 0; j < 4; ++j)
          acc[i][j] = __builtin_amdgcn_mfma_f32_16x16x32_f16(aF[i], bF[j], acc[i][j], 0, 0, 0);
    }
    __syncthreads();
  }
  int f32out = (MODE == 2) ? dtf[0] : 0;
  const float L2E = 1.44269504088896340736f;
  #pragma unroll
  for (int j = 0; j < 4; ++j){
    uint col = bn*128u + wn*64u + j*16u + l15;
    float bj = bias[col];
    #pragma unroll
    for (int i = 0; i < 4; ++i){
      uint row0 = bm*128u + wm*64u + i*16u + quad*4u;
      #pragma unroll
      for (int r = 0; r < 4; ++r){
        float val = acc[i][j][r] + bj;
        uint row = row0 + r;
        if (MODE == 0){
          ((ushort*)Cv)[(size_t)row*N + col] = f2h(val);
        } else if (MODE == 3){
          float v2 = cb ? val * L2E : val;   // q-half pre-scaled by log2(e)
          ((ushort*)Cv)[(size_t)row*2048u + (uint)cb + col] = f2h(v2);
        } else if (MODE == 4){
          // col = h*64+e ; row = b*512+s
          Vt[(size_t)(((row >> 9)*16u + (col >> 6))*64u + (col & 63u))*512u + (row & 511u)] = f2h(val);
        } else {
          if (f32out) ((float*)Cv)[(size_t)row*N + col] = val;
          else        ((ushort*)Cv)[(size_t)row*N + col] = f2bf(val);
        }
      }
    }
  }
}

// ---------------- fused attention ("transposed" causal, flash-style) ---------
// S[t,s] = K[t,:]·Q[s,:], keep s<=t, softmax over s, O[t,:] = sum_s P[t,s]V[s,:]
// kq: fp16 [16384][2048] (q pre-scaled by log2e); Vt: fp16 [(b*16+h)*64+e][512]
// S is already in log2 domain -> exp2 directly.
// LDS 32 KB (was 40): sQ double-buffered (full-iter prefetch), sV SINGLE-
// buffered with counted vmcnt: V[st] loads are issued FIRST at iter start,
// Q[st+1] prefetch after -> s_waitcnt vmcnt(2) before PV retires exactly the
// V pair while Q stays in flight (T4). 160/32 = 5 blocks/CU (20 waves, was
// 12) -> more TLP for the VALU-bound softmax + latency hiding.
// LPT: heavy (large tt) blocks launch first; light blocks backfill the tail.
__global__ __launch_bounds__(256, 5) void kattn(const ushort* __restrict__ kq,
                                                const ushort* __restrict__ Vt,
                                                ushort* __restrict__ Out){
  __shared__ ushort sQ[2][64*64];          // [s-local][d] swizzled   16 KB
  __shared__ ushort sV[64*64];             // [e][s-local] swizzled    8 KB
  __shared__ ushort pbuf[4][16*64];        // per-wave P; K staging    8 KB
  uint tid = threadIdx.x, w = tid >> 6, lane = tid & 63u, quad = lane >> 4, l15 = lane & 15u;
  uint bh = blockIdx.x, tt = 7u - blockIdx.y;   // LPT: heavy tiles first
  uint b = bh >> 4, h = bh & 15u;
  uint t0 = tt*64u;
  const float MNEG = -1.0e30f;

  // stage K tile [t-local][d] into pbuf, Q0 into buf 0 (swizzled)
  stage64(kq + (size_t)(b*512u + t0)*2048u + h*64u, 2048u, (ushort*)pbuf, tid);
  stage64(kq + (size_t)(b*512u)*2048u + 1024u + h*64u, 2048u, sQ[0], tid);   // s0=0
  __syncthreads();

  f16x8 aK[2];  // K rows for this wave's 16 t's (wave-own pbuf rows)
  aK[0] = ld16(swz((const ushort*)pbuf, w*16u + l15, quad));
  aK[1] = ld16(swz((const ushort*)pbuf, w*16u + l15, 4u + quad));

  float m[4], l[4];
  f32x4 oacc[4];
  #pragma unroll
  for (int r = 0; r < 4; ++r){ m[r] = MNEG; l[r] = 0.f; }
  #pragma unroll
  for (int je = 0; je < 4; ++je) oacc[je] = (f32x4){0.f, 0.f, 0.f, 0.f};

  ushort* pw = (ushort*)pbuf + w*1024u;    // wave-private P region

  for (uint st = 0; st <= tt; ++st){
    uint cur = st & 1u;
    if (st) __syncthreads();               // drains Q[st] prefetch; prev sV readers done
    // V[st] stage FIRST (2 loads/thread), then Q[st+1] prefetch (2 loads/thread)
    stage64(Vt + (size_t)(bh*64u)*512u + st*64u, 512u, sV, tid);
    if (st < tt)
      stage64(kq + (size_t)(b*512u + (st + 1u)*64u)*2048u + 1024u + h*64u, 2048u, sQ[cur ^ 1u], tid);
    f32x4 sacc[4];
    #pragma unroll
    for (int j = 0; j < 4; ++j){
      f16x8 bq0 = ld16(swz(sQ[cur], j*16u + l15, quad));
      f16x8 bq1 = ld16(swz(sQ[cur], j*16u + l15, 4u + quad));
      f32x4 s = (f32x4){0.f, 0.f, 0.f, 0.f};
      s = __builtin_amdgcn_mfma_f32_16x16x32_f16(aK[0], bq0, s, 0, 0, 0);
      s = __builtin_amdgcn_mfma_f32_16x16x32_f16(aK[1], bq1, s, 0, 0, 0);
      sacc[j] = s;
    }
    if (st == tt){  // diagonal tile: keep s<=t
      #pragma unroll
      for (int j = 0; j < 4; ++j)
        #pragma unroll
        for (int r = 0; r < 4; ++r)
          if (j*16u + l15 > w*16u + quad*4u + (uint)r) sacc[j][r] = MNEG;
    }
    float alpha[4];
    #pragma unroll
    for (int r = 0; r < 4; ++r){
      float v = fmaxf(fmaxf(sacc[0][r], sacc[1][r]), fmaxf(sacc[2][r], sacc[3][r]));
      v = fmaxf(v, __shfl_xor(v, 1));
      v = fmaxf(v, __shfl_xor(v, 2));
      v = fmaxf(v, __shfl_xor(v, 4));
      v = fmaxf(v, __shfl_xor(v, 8));
      float mn = fmaxf(m[r], v);
      alpha[r] = exp2f(m[r] - mn);         // already log2-domain
      m[r] = mn;
    }
    #pragma unroll
    for (int j = 0; j < 4; ++j)
      #pragma unroll
      for (int r = 0; r < 4; ++r)
        sacc[j][r] = exp2f(sacc[j][r] - m[r]);
    #pragma unroll
    for (int r = 0; r < 4; ++r){
      float s = sacc[0][r] + sacc[1][r] + sacc[2][r] + sacc[3][r];
      s += __shfl_xor(s, 1);
      s += __shfl_xor(s, 2);
      s += __shfl_xor(s, 4);
      s += __shfl_xor(s, 8);
      l[r] = l[r]*alpha[r] + s;
    }
    #pragma unroll
    for (int je = 0; je < 4; ++je)
      #pragma unroll
      for (int r = 0; r < 4; ++r)
        oacc[je][r] *= alpha[r];
    // P: C/D layout -> wave-private swizzled LDS -> A-operand frags (no barrier)
    #pragma unroll
    for (int j = 0; j < 4; ++j)
      #pragma unroll
      for (int r = 0; r < 4; ++r){
        uint t = quad*4u + (uint)r;
        pw[t*64u + (((j*2u + (l15 >> 3)) ^ (t & 7u))*8u) + (l15 & 7u)] = f2h(sacc[j][r]);
      }
    f16x8 aP0 = ld16(swz(pw, l15, quad));
    f16x8 aP1 = ld16(swz(pw, l15, 4u + quad));
    // V[st] must be resident: retire the 2 V loads; Q prefetch (2) stays in flight
    if (st < tt) { asm volatile("s_waitcnt vmcnt(2)" ::: "memory"); }
    else         { asm volatile("s_waitcnt vmcnt(0)" ::: "memory"); }
    #pragma unroll
    for (int je = 0; je < 4; ++je){
      f16x8 bv0 = ld16(swz(sV, je*16u + l15, quad));
      f16x8 bv1 = ld16(swz(sV, je*16u + l15, 4u + quad));
      oacc[je] = __builtin_amdgcn_mfma_f32_16x16x32_f16(aP0, bv0, oacc[je], 0, 0, 0);
      oacc[je] = __builtin_amdgcn_mfma_f32_16x16x32_f16(aP1, bv1, oacc[je], 0, 0, 0);
    }
  }
  float inv[4];
  #pragma unroll
  for (int r = 0; r < 4; ++r) inv[r] = 1.0f / l[r];
  #pragma unroll
  for (int je = 0; je < 4; ++je){
    uint e = h*64u + je*16u + l15;
    #pragma unroll
    for (int r = 0; r < 4; ++r){
      uint t = t0 + w*16u + quad*4u + (uint)r;
      Out[(size_t)(b*512u + t)*1024u + e] = f2h(oacc[je][r]*inv[r]);
    }
  }
}

// ---------------- launcher ---------------------------------------------------

extern "C" void kernel_launch(void* const* d_in, const int* in_sizes, int n_in,
                              void* d_out, int out_size, void* d_ws, size_t ws_size,
                              hipStream_t stream){
  const void* x  = d_in[0];
  const void* Wi = d_in[1];
  const void* bi = d_in[2];
  const void* Wk = d_in[3];
  const void* bk = d_in[4];
  const void* Wq = d_in[5];
  const void* bq = d_in[6];
  const void* Wv = d_in[7];
  const void* bv = d_in[8];
  const void* Wo = d_in[9];
  const void* bo = d_in[10];
  char* ws = (char*)d_ws;

  const size_t MB = 1u << 20;
  int*    flag   = (int*)ws;
  float*  bi_f   = (float*)(ws + 4096);                  // 4 KB
  float*  bo_f   = (float*)(ws + 8192);                  // 4 KB
  float*  bqkv_f = (float*)(ws + 12288);                 // 12 KB
  ushort* WiT    = (ushort*)(ws + 32768);                // 2 MB  (fp16)
  ushort* WoT    = (ushort*)(ws + 32768 + 2*MB);         // 2 MB
  ushort* WqkvT  = (ushort*)(ws + 32768 + 4*MB);         // 6 MB
  ushort* xh     = (ushort*)(ws + 32768 + 10*MB);        // 32 MB (dead after GEMM0)
  ushort* kq     = (ushort*)(ws + 32768 + 10*MB);        // 64 MB (overlays xh)
  ushort* hbuf   = (ushort*)(ws + 32768 + 74*MB);        // 32 MB (h, then attn out)
  ushort* Vt     = (ushort*)(ws + 32768 + 106*MB);       // 32 MB -> total ~138 MB

  kprep<<<dim3(9492), dim3(256), 0, stream>>>(x, Wi, Wo, Wk, Wq, Wv, bi, bo, bk, bq, bv,
                                              flag, bi_f, bo_f, bqkv_f, xh, WiT, WoT, WqkvT);

  kgemm<0><<<dim3(128, 8), dim3(256), 0, stream>>>(xh,   WiT, bi_f, hbuf, nullptr, nullptr, NTOK, 1024, 1024, 0);
  kgemm<3><<<dim3(128, 8), dim3(256), 0, stream>>>(hbuf, WqkvT,                      bqkv_f,        kq, nullptr, nullptr, NTOK, 1024, 1024, 0);
  kgemm<3><<<dim3(128, 8), dim3(256), 0, stream>>>(hbuf, WqkvT + (size_t)1024*1024,  bqkv_f + 1024, kq, nullptr, nullptr, NTOK, 1024, 1024, 1024);
  kgemm<4><<<dim3(128, 8), dim3(256), 0, stream>>>(hbuf, WqkvT + (size_t)2048*1024,  bqkv_f + 2048, nullptr, Vt, nullptr, NTOK, 1024, 1024, 0);
  kattn<<<dim3(512, 8), dim3(256), 0, stream>>>(kq, Vt, hbuf);
  kgemm<2><<<dim3(128, 8), dim3(256), 0, stream>>>(hbuf, WoT, bo_f, d_out, nullptr, flag, NTOK, 1024, 1024, 0);
}